// Round 10
// baseline (87.067 us; speedup 1.0000x reference)
//
#include <hip/hip_runtime.h>
#include <stdint.h>

// Geometry fixed by the reference: A bits [4,512,512,32], B bits [512,512,32]
#define BATCH 4
#define MDIM  512
#define KDIM  512
#define NDIM  512
#define ROWS  (BATCH * MDIM)   // 2048 flattened output rows
#define BR    4                // C rows per block (4 accs/thread) -> 4096 waves
#define BCOLS 256              // C cols per block (1 col/thread)

#define WORDS_A (ROWS * KDIM)        // 1,048,576 decoded fp32 words of A
#define WORDS_B (KDIM * NDIM)        //   262,144 decoded fp32 words of B
#define WORDS_T (WORDS_A + WORDS_B)  // 1,310,720
#define DEC_BLOCKS 2048
#define DEC_WAVES  (DEC_BLOCKS * 4)              // 8192 waves
#define DEC_ITERS  (WORDS_T / (32 * DEC_WAVES))  // 5 (exact)

// Spread 8 bits so bit i lands at position 4*i (exact integer op).
__device__ __forceinline__ uint32_t spread4(uint32_t x) {
    x = (x | (x << 12)) & 0x000F000Fu;
    x = (x | (x << 6))  & 0x03030303u;
    x = (x | (x << 3))  & 0x11111111u;
    return x;
}

// ---------------------------------------------------------------------------
// Decode: pulse bits (float {0,1}, bit0=LSB) -> u32 words, fully coalesced.
// Static trip count (5), 4 KiB/wave/iter via four independent uint4/lane.
// Bit of v is bit29 of its IEEE pattern (1.0f = 0x3F800000). Four __ballot
// per KiB collect the wave's 256 bits; lanes (lane&7)==0 assemble 4 words
// each. Integer-exact.
// ---------------------------------------------------------------------------
__global__ __launch_bounds__(256) void decode_all(const float* __restrict__ Abits,
                                                  const float* __restrict__ Bbits,
                                                  uint32_t* __restrict__ Au,
                                                  uint32_t* __restrict__ Bu) {
    const int lane = threadIdx.x & 63;
    const int waveId = (blockIdx.x * blockDim.x + threadIdx.x) >> 6;
    const int sh = lane & 56;                 // 8*(lane>>3)

#pragma unroll
    for (int i = 0; i < DEC_ITERS; ++i) {
        const int wb = (waveId + i * DEC_WAVES) * 32;   // 32 words per wave-iter
        const float* src;
        uint32_t* dst;
        if (wb < WORDS_A) { src = Abits + (size_t)wb * 32;             dst = Au + wb; }
        else              { src = Bbits + (size_t)(wb - WORDS_A) * 32; dst = Bu + (wb - WORDS_A); }

        uint4 v0 = ((const uint4*)src)[lane];         // KiB 0: words  0..7
        uint4 v1 = ((const uint4*)src)[lane + 64];    // KiB 1: words  8..15
        uint4 v2 = ((const uint4*)src)[lane + 128];   // KiB 2: words 16..23
        uint4 v3 = ((const uint4*)src)[lane + 192];   // KiB 3: words 24..31

        unsigned long long m[16];
        m[0]  = __ballot((v0.x >> 29) & 1u);  m[1]  = __ballot((v0.y >> 29) & 1u);
        m[2]  = __ballot((v0.z >> 29) & 1u);  m[3]  = __ballot((v0.w >> 29) & 1u);
        m[4]  = __ballot((v1.x >> 29) & 1u);  m[5]  = __ballot((v1.y >> 29) & 1u);
        m[6]  = __ballot((v1.z >> 29) & 1u);  m[7]  = __ballot((v1.w >> 29) & 1u);
        m[8]  = __ballot((v2.x >> 29) & 1u);  m[9]  = __ballot((v2.y >> 29) & 1u);
        m[10] = __ballot((v2.z >> 29) & 1u);  m[11] = __ballot((v2.w >> 29) & 1u);
        m[12] = __ballot((v3.x >> 29) & 1u);  m[13] = __ballot((v3.y >> 29) & 1u);
        m[14] = __ballot((v3.z >> 29) & 1u);  m[15] = __ballot((v3.w >> 29) & 1u);

        if ((lane & 7) == 0) {
#pragma unroll
            for (int g = 0; g < 4; ++g) {
                uint32_t w = (spread4((uint32_t)(m[4*g+0] >> sh) & 0xFFu) << 0)
                           | (spread4((uint32_t)(m[4*g+1] >> sh) & 0xFFu) << 1)
                           | (spread4((uint32_t)(m[4*g+2] >> sh) & 0xFFu) << 2)
                           | (spread4((uint32_t)(m[4*g+3] >> sh) & 0xFFu) << 3);
                dst[8 * g + (lane >> 3)] = w;
            }
        }
    }
}

// ---------------------------------------------------------------------------
// LDS-free GEMM k-loop (exact np.einsum semantics: per output element, single
// accumulator, k ascending, one FMA per step) + LDS-transposed coalesced
// bit-encode epilogue.
// Block: 4 rows x 256 cols, 256 threads; thread = 1 col, 4 row-accs.
// A loads wave-uniform (scalar path); B loads lane-coalesced & L2-resident,
// with a 4-DEEP rotating register prefetch pipeline (32 B-values in flight
// per wave; load-to-use distance ~3 compute phases >> L2 latency).
// #pragma unroll 4 keeps all buffer indices compile-time-static (no scratch).
// Epilogue: accs -> 4 KiB LDS, 1 barrier, then 128 KiB/block written with
// consecutive-lane float4 stores (wave-contiguous).
// ---------------------------------------------------------------------------
__global__ __launch_bounds__(256) void gemm_encode(const float* __restrict__ A,
                                                   const float* __restrict__ B,
                                                   float* __restrict__ outbits) {
    __shared__ uint32_t Us[BR][BCOLS];   // 4 KiB

    const int tid = threadIdx.x;
    const int rowBase = blockIdx.x * BR;
    const int n0 = blockIdx.y * BCOLS;
    const int n = n0 + tid;

    float acc[BR];
#pragma unroll
    for (int r = 0; r < BR; ++r) acc[r] = 0.0f;

    const float* Bcol = B + n;
    const float* Arow = A + (size_t)rowBase * KDIM;

    // 4-deep rotating B prefetch: buf[j] holds k-group (g0+j) for the
    // current iteration's base group g0. 64 groups of 8 k's total.
    float buf[4][8];
#pragma unroll
    for (int j = 0; j < 4; ++j)
#pragma unroll
        for (int i = 0; i < 8; ++i)
            buf[j][i] = Bcol[(size_t)(j * 8 + i) * NDIM];

#pragma unroll 4
    for (int g = 0; g < KDIM / 8; ++g) {          // base k = 8*g
        const int k0 = g * 8;
        // A: wave-uniform scalar loads for this group.
        float4 a0[BR], a1[BR];
#pragma unroll
        for (int r = 0; r < BR; ++r) {
            a0[r] = *(const float4*)(Arow + (size_t)r * KDIM + k0);
            a1[r] = *(const float4*)(Arow + (size_t)r * KDIM + k0 + 4);
        }
        // Consume group g from buf[g&3] (k ascending; one FMA per step).
#pragma unroll
        for (int r = 0; r < BR; ++r) {
            acc[r] = __builtin_fmaf(a0[r].x, buf[g & 3][0], acc[r]);
            acc[r] = __builtin_fmaf(a0[r].y, buf[g & 3][1], acc[r]);
            acc[r] = __builtin_fmaf(a0[r].z, buf[g & 3][2], acc[r]);
            acc[r] = __builtin_fmaf(a0[r].w, buf[g & 3][3], acc[r]);
            acc[r] = __builtin_fmaf(a1[r].x, buf[g & 3][4], acc[r]);
            acc[r] = __builtin_fmaf(a1[r].y, buf[g & 3][5], acc[r]);
            acc[r] = __builtin_fmaf(a1[r].z, buf[g & 3][6], acc[r]);
            acc[r] = __builtin_fmaf(a1[r].w, buf[g & 3][7], acc[r]);
        }
        // Refill buf[g&3] with group g+4 (wraps on the last 4 iters; the
        // reloaded values are never consumed — harmless, keeps code branchless).
        const int kp = (k0 + 32) & (KDIM - 1);
#pragma unroll
        for (int i = 0; i < 8; ++i)
            buf[g & 3][i] = Bcol[(size_t)(kp + i) * NDIM];
    }

    // ---- epilogue: transpose through LDS, then coalesced bit stores ----
#pragma unroll
    for (int r = 0; r < BR; ++r) Us[r][tid] = __float_as_uint(acc[r]);
    __syncthreads();

    float* oBase = outbits + ((size_t)rowBase * NDIM + n0) * 32;
    const int b = (tid & 7) * 4;
#pragma unroll
    for (int r = 0; r < BR; ++r) {
        float* o = oBase + (size_t)r * NDIM * 32;
#pragma unroll
        for (int it = 0; it < 8; ++it) {
            uint32_t u = Us[r][it * 32 + (tid >> 3)];   // 8-lane broadcast
            float4 q;
            q.x = (float)((u >> (b + 0)) & 1u);
            q.y = (float)((u >> (b + 1)) & 1u);
            q.z = (float)((u >> (b + 2)) & 1u);
            q.w = (float)((u >> (b + 3)) & 1u);
            *(float4*)(o + it * 1024 + tid * 4) = q;    // lanes contiguous
        }
    }
}

extern "C" void kernel_launch(void* const* d_in, const int* in_sizes, int n_in,
                              void* d_out, int out_size, void* d_ws, size_t ws_size,
                              hipStream_t stream) {
    const float* Abits = (const float*)d_in[0];   // [4,512,512,32] floats {0,1}
    const float* Bbits = (const float*)d_in[1];   // [512,512,32]
    float* out = (float*)d_out;                   // [4,512,512,32]

    // Workspace: A_u32 (4 MiB) | B_u32 (1 MiB)
    uint32_t* A_u = (uint32_t*)d_ws;
    uint32_t* B_u = A_u + WORDS_A;

    decode_all<<<DEC_BLOCKS, 256, 0, stream>>>(Abits, Bbits, A_u, B_u);

    dim3 grid(ROWS / BR, NDIM / BCOLS);           // (512, 2) = 1024 blocks
    gemm_encode<<<grid, 256, 0, stream>>>((const float*)A_u, (const float*)B_u, out);
}

// Round 12
// 82.309 us; speedup vs baseline: 1.0578x; 1.0578x over previous
//
#include <hip/hip_runtime.h>
#include <stdint.h>

// Geometry fixed by the reference: A bits [4,512,512,32], B bits [512,512,32]
#define BATCH 4
#define MDIM  512
#define KDIM  512
#define NDIM  512
#define ROWS  (BATCH * MDIM)   // 2048 flattened output rows
#define BR    4                // C rows per block (4 accs/thread) -> 4096 waves
#define BCOLS 256              // C cols per block (1 col/thread)

#define WORDS_A (ROWS * KDIM)        // 1,048,576 decoded fp32 words of A
#define WORDS_B (KDIM * NDIM)        //   262,144 decoded fp32 words of B
#define WORDS_T (WORDS_A + WORDS_B)  // 1,310,720
#define DEC_BLOCKS 2048
#define DEC_WAVES  (DEC_BLOCKS * 4)              // 8192 waves
#define DEC_ITERS  (WORDS_T / (32 * DEC_WAVES))  // 5 (exact)

// Native vector types accepted by __builtin_nontemporal_load/store.
typedef unsigned int u32x4 __attribute__((ext_vector_type(4)));
typedef float        f32x4 __attribute__((ext_vector_type(4)));

// Spread 8 bits so bit i lands at position 4*i (exact integer op).
__device__ __forceinline__ uint32_t spread4(uint32_t x) {
    x = (x | (x << 12)) & 0x000F000Fu;
    x = (x | (x << 6))  & 0x03030303u;
    x = (x | (x << 3))  & 0x11111111u;
    return x;
}

// ---------------------------------------------------------------------------
// Decode: pulse bits (float {0,1}, bit0=LSB) -> u32 words, fully coalesced.
// Input is streamed ONCE -> non-temporal loads (don't pollute L2).
// Static trip count (5), 4 KiB/wave/iter via four independent 16B/lane.
// Bit of v is bit29 of its IEEE pattern (1.0f = 0x3F800000). Four __ballot
// per KiB collect the wave's 256 bits; lanes (lane&7)==0 assemble 4 words
// each. Integer-exact.
// ---------------------------------------------------------------------------
__global__ __launch_bounds__(256) void decode_all(const float* __restrict__ Abits,
                                                  const float* __restrict__ Bbits,
                                                  uint32_t* __restrict__ Au,
                                                  uint32_t* __restrict__ Bu) {
    const int lane = threadIdx.x & 63;
    const int waveId = (blockIdx.x * blockDim.x + threadIdx.x) >> 6;
    const int sh = lane & 56;                 // 8*(lane>>3)

#pragma unroll
    for (int i = 0; i < DEC_ITERS; ++i) {
        const int wb = (waveId + i * DEC_WAVES) * 32;   // 32 words per wave-iter
        const float* src;
        uint32_t* dst;
        if (wb < WORDS_A) { src = Abits + (size_t)wb * 32;             dst = Au + wb; }
        else              { src = Bbits + (size_t)(wb - WORDS_A) * 32; dst = Bu + (wb - WORDS_A); }

        const u32x4* sp = (const u32x4*)src;
        u32x4 v0 = __builtin_nontemporal_load(sp + lane);         // KiB 0: words  0..7
        u32x4 v1 = __builtin_nontemporal_load(sp + lane + 64);    // KiB 1: words  8..15
        u32x4 v2 = __builtin_nontemporal_load(sp + lane + 128);   // KiB 2: words 16..23
        u32x4 v3 = __builtin_nontemporal_load(sp + lane + 192);   // KiB 3: words 24..31

        unsigned long long m[16];
        m[0]  = __ballot((v0.x >> 29) & 1u);  m[1]  = __ballot((v0.y >> 29) & 1u);
        m[2]  = __ballot((v0.z >> 29) & 1u);  m[3]  = __ballot((v0.w >> 29) & 1u);
        m[4]  = __ballot((v1.x >> 29) & 1u);  m[5]  = __ballot((v1.y >> 29) & 1u);
        m[6]  = __ballot((v1.z >> 29) & 1u);  m[7]  = __ballot((v1.w >> 29) & 1u);
        m[8]  = __ballot((v2.x >> 29) & 1u);  m[9]  = __ballot((v2.y >> 29) & 1u);
        m[10] = __ballot((v2.z >> 29) & 1u);  m[11] = __ballot((v2.w >> 29) & 1u);
        m[12] = __ballot((v3.x >> 29) & 1u);  m[13] = __ballot((v3.y >> 29) & 1u);
        m[14] = __ballot((v3.z >> 29) & 1u);  m[15] = __ballot((v3.w >> 29) & 1u);

        if ((lane & 7) == 0) {
#pragma unroll
            for (int g = 0; g < 4; ++g) {
                uint32_t w = (spread4((uint32_t)(m[4*g+0] >> sh) & 0xFFu) << 0)
                           | (spread4((uint32_t)(m[4*g+1] >> sh) & 0xFFu) << 1)
                           | (spread4((uint32_t)(m[4*g+2] >> sh) & 0xFFu) << 2)
                           | (spread4((uint32_t)(m[4*g+3] >> sh) & 0xFFu) << 3);
                dst[8 * g + (lane >> 3)] = w;    // cached: consumed by gemm
            }
        }
    }
}

// ---------------------------------------------------------------------------
// LDS-free GEMM k-loop (exact np.einsum semantics: per output element, single
// accumulator, k ascending, one FMA per step) + LDS-transposed coalesced
// bit-encode epilogue with NON-TEMPORAL stores (134 MB streamed once; keep
// it out of L2 so B_u/A_u stay resident for the k-phase).
// Block: 4 rows x 256 cols, 256 threads; thread = 1 col, 4 row-accs.
// A loads wave-uniform (scalar path); B loads lane-coalesced & L2-resident,
// 1-group-ahead register prefetch (R8 structure, measured best).
// ---------------------------------------------------------------------------
__global__ __launch_bounds__(256) void gemm_encode(const float* __restrict__ A,
                                                   const float* __restrict__ B,
                                                   float* __restrict__ outbits) {
    __shared__ uint32_t Us[BR][BCOLS];   // 4 KiB

    const int tid = threadIdx.x;
    const int rowBase = blockIdx.x * BR;
    const int n0 = blockIdx.y * BCOLS;
    const int n = n0 + tid;

    float acc[BR];
#pragma unroll
    for (int r = 0; r < BR; ++r) acc[r] = 0.0f;

    const float* Bcol = B + n;
    const float* Arow = A + (size_t)rowBase * KDIM;

    float bn[8], bc[8];
#pragma unroll
    for (int i = 0; i < 8; ++i) bn[i] = Bcol[(size_t)i * NDIM];   // prologue

#pragma unroll 2
    for (int k0 = 0; k0 < KDIM; k0 += 8) {
#pragma unroll
        for (int i = 0; i < 8; ++i) bc[i] = bn[i];
        const int kp = (k0 + 8) & (KDIM - 1);    // wraps on last iter (harmless)
#pragma unroll
        for (int i = 0; i < 8; ++i) bn[i] = Bcol[(size_t)(kp + i) * NDIM];

        float4 a0[BR], a1[BR];
#pragma unroll
        for (int r = 0; r < BR; ++r) {
            a0[r] = *(const float4*)(Arow + (size_t)r * KDIM + k0);
            a1[r] = *(const float4*)(Arow + (size_t)r * KDIM + k0 + 4);
        }
        // k ascending per element; one FMA per step.
#pragma unroll
        for (int r = 0; r < BR; ++r) {
            acc[r] = __builtin_fmaf(a0[r].x, bc[0], acc[r]);
            acc[r] = __builtin_fmaf(a0[r].y, bc[1], acc[r]);
            acc[r] = __builtin_fmaf(a0[r].z, bc[2], acc[r]);
            acc[r] = __builtin_fmaf(a0[r].w, bc[3], acc[r]);
            acc[r] = __builtin_fmaf(a1[r].x, bc[4], acc[r]);
            acc[r] = __builtin_fmaf(a1[r].y, bc[5], acc[r]);
            acc[r] = __builtin_fmaf(a1[r].z, bc[6], acc[r]);
            acc[r] = __builtin_fmaf(a1[r].w, bc[7], acc[r]);
        }
    }

    // ---- epilogue: transpose through LDS, then coalesced NT bit stores ----
#pragma unroll
    for (int r = 0; r < BR; ++r) Us[r][tid] = __float_as_uint(acc[r]);
    __syncthreads();

    float* oBase = outbits + ((size_t)rowBase * NDIM + n0) * 32;
    const int b = (tid & 7) * 4;
#pragma unroll
    for (int r = 0; r < BR; ++r) {
        float* o = oBase + (size_t)r * NDIM * 32;
#pragma unroll
        for (int it = 0; it < 8; ++it) {
            uint32_t u = Us[r][it * 32 + (tid >> 3)];   // 8-lane broadcast
            f32x4 q;
            q.x = (float)((u >> (b + 0)) & 1u);
            q.y = (float)((u >> (b + 1)) & 1u);
            q.z = (float)((u >> (b + 2)) & 1u);
            q.w = (float)((u >> (b + 3)) & 1u);
            __builtin_nontemporal_store(q, (f32x4*)(o + it * 1024 + tid * 4));
        }
    }
}

extern "C" void kernel_launch(void* const* d_in, const int* in_sizes, int n_in,
                              void* d_out, int out_size, void* d_ws, size_t ws_size,
                              hipStream_t stream) {
    const float* Abits = (const float*)d_in[0];   // [4,512,512,32] floats {0,1}
    const float* Bbits = (const float*)d_in[1];   // [512,512,32]
    float* out = (float*)d_out;                   // [4,512,512,32]

    // Workspace: A_u32 (4 MiB) | B_u32 (1 MiB)
    uint32_t* A_u = (uint32_t*)d_ws;
    uint32_t* B_u = A_u + WORDS_A;

    decode_all<<<DEC_BLOCKS, 256, 0, stream>>>(Abits, Bbits, A_u, B_u);

    dim3 grid(ROWS / BR, NDIM / BCOLS);           // (512, 2) = 1024 blocks
    gemm_encode<<<grid, 256, 0, stream>>>((const float*)A_u, (const float*)B_u, out);
}